// Round 12
// baseline (166.349 us; speedup 1.0000x reference)
//
#include <hip/hip_runtime.h>
#include <hip/hip_bf16.h>
#include <math.h>

typedef __attribute__((ext_vector_type(8))) short short8;
typedef __attribute__((ext_vector_type(4))) float f32x4;
typedef __attribute__((ext_vector_type(16))) float f32x16;
typedef __attribute__((ext_vector_type(2))) unsigned uint2v;
typedef __attribute__((ext_vector_type(4))) unsigned uint4v;

#define B_  4
#define T_  2048
#define DM  1024
#define NH  16
#define DH  64
#define BH  (B_*NH)   // 64
#define M_  (B_*T_)   // 8192

// 1/sqrt(64) * log2(e): folded into Q at QKV-GEMM epilogue so attention scores
// come out of MFMA already in exp2-ready units.
#define QSCALE 0.18033688011112042f

static __device__ __forceinline__ short f2bf(float f) {
  unsigned u = __float_as_uint(f);
  unsigned r = (u + 0x7fff + ((u >> 16) & 1)) >> 16;
  return (short)r;
}

static __device__ __forceinline__ float bf2f(short s) {
  return __uint_as_float(((unsigned)(unsigned short)s) << 16);
}

static __device__ __forceinline__ unsigned cvtpk(float lo, float hi) {
  unsigned r;
  asm("v_cvt_pk_bf16_f32 %0, %1, %2" : "=v"(r) : "v"(lo), "v"(hi));
  return r;
}

static __device__ __forceinline__ float expasm(float x) {
  float r;
  asm("v_exp_f32 %0, %1" : "=v"(r) : "v"(x));
  return r;
}

static __device__ __forceinline__ void gload_lds16(const void* g, void* l) {
  __builtin_amdgcn_global_load_lds((const __attribute__((address_space(1))) void*)g,
                                   (__attribute__((address_space(3))) void*)l, 16, 0, 0);
}

// ---------------- fp32 -> bf16 convert, all three tensors in one launch ----------------
__global__ void k_cvt3(const float4* __restrict__ x, const float4* __restrict__ wq,
                       const float4* __restrict__ wp, ushort4* __restrict__ ox,
                       ushort4* __restrict__ oq, ushort4* __restrict__ op) {
  const int n1 = M_ * DM / 4, n2 = 3 * DM * DM / 4, n3 = DM * DM / 4;
  int i = blockIdx.x * 256 + threadIdx.x;
  const float4* src;
  ushort4* dst;
  int j = i;
  if (i < n1) { src = x; dst = ox; }
  else if (i < n1 + n2) { src = wq; dst = oq; j = i - n1; }
  else if (i < n1 + n2 + n3) { src = wp; dst = op; j = i - n1 - n2; }
  else return;
  float4 v = src[j];
  ushort4 o;
  o.x = (ushort)f2bf(v.x); o.y = (ushort)f2bf(v.y);
  o.z = (ushort)f2bf(v.z); o.w = (ushort)f2bf(v.w);
  dst[j] = o;
}

// ================= GEMM core macros (128x128 tile, BK=64, dbuf, swizzled) =================
#define GEMM_STAGE(SRCA, SRCB, dA, dB, m0_, n0_, k0_)                          \
  {                                                                            \
    _Pragma("unroll")                                                          \
    for (int i = 0; i < 4; ++i) {                                              \
      int lin = i * 256 + tid;                                                 \
      int row = lin >> 3, pseg = lin & 7;                                      \
      int gseg = pseg ^ (row & 7);                                             \
      gload_lds16(&SRCA[(size_t)((m0_) + row) * DM + (k0_) + gseg * 8],        \
                  &(dA)[lin * 8]);                                             \
    }                                                                          \
    _Pragma("unroll")                                                          \
    for (int i = 0; i < 4; ++i) {                                              \
      int lin = i * 256 + tid;                                                 \
      int row = lin >> 3, pseg = lin & 7;                                      \
      int gseg = pseg ^ (row & 7);                                             \
      gload_lds16(&SRCB[(size_t)((n0_) + row) * DM + (k0_) + gseg * 8],        \
                  &(dB)[lin * 8]);                                             \
    }                                                                          \
  }

#define GEMM_COMPUTE(pA, pB)                                                   \
  {                                                                            \
    _Pragma("unroll")                                                          \
    for (int kk = 0; kk < 2; ++kk) {                                           \
      short8 aF[4], bF[4];                                                     \
      _Pragma("unroll")                                                        \
      for (int m = 0; m < 4; ++m)                                              \
        aF[m] = *(const short8*)&(pA)[(wr * 64 + m * 16 + fr) * 64 +           \
                                      (((kk * 4 + fq) ^ (fr & 7)) * 8)];       \
      _Pragma("unroll")                                                        \
      for (int n = 0; n < 4; ++n)                                              \
        bF[n] = *(const short8*)&(pB)[(wc * 64 + n * 16 + fr) * 64 +           \
                                      (((kk * 4 + fq) ^ (fr & 7)) * 8)];       \
      __builtin_amdgcn_s_setprio(1);                                           \
      _Pragma("unroll")                                                        \
      for (int m = 0; m < 4; ++m)                                              \
        _Pragma("unroll")                                                      \
        for (int n = 0; n < 4; ++n)                                            \
          acc[m][n] = __builtin_amdgcn_mfma_f32_16x16x32_bf16(aF[m], bF[n],    \
                                                              acc[m][n], 0, 0, 0); \
      __builtin_amdgcn_s_setprio(0);                                           \
    }                                                                          \
  }

#define GEMM_KLOOP(SRCA, SRCB, m0_, n0_)                                       \
  GEMM_STAGE(SRCA, SRCB, sA0, sB0, m0_, n0_, 0);                               \
  {                                                                            \
    _Pragma("unroll 1")                                                        \
    for (int t = 0; t < 16; ++t) {                                             \
      short* pA = (t & 1) ? sA1 : sA0;                                         \
      short* pB = (t & 1) ? sB1 : sB0;                                         \
      if (t < 15) {                                                            \
        short* nA = (t & 1) ? sA0 : sA1;                                       \
        short* nB = (t & 1) ? sB0 : sB1;                                       \
        GEMM_STAGE(SRCA, SRCB, nA, nB, m0_, n0_, (t + 1) * 64);                \
        asm volatile("s_waitcnt vmcnt(8)" ::: "memory");                       \
      } else {                                                                 \
        asm volatile("s_waitcnt vmcnt(0)" ::: "memory");                       \
      }                                                                        \
      __builtin_amdgcn_s_barrier();                                            \
      __builtin_amdgcn_sched_barrier(0);                                       \
      GEMM_COMPUTE(pA, pB);                                                    \
      asm volatile("" ::: "memory");                                           \
      __builtin_amdgcn_s_barrier();                                            \
    }                                                                          \
  }

// ---------------- QKV GEMM ----------------
// Q (scaled by QSCALE), K -> [bh][t][dh]; V -> transposed [bh][dh][t].
__global__ __launch_bounds__(256, 2) void k_gemm_qkv(
    const short* __restrict__ A,    // [M_, DM]
    const short* __restrict__ W,    // [3*DM, DM]
    short* __restrict__ Qb, short* __restrict__ Kb, short* __restrict__ Vtb) {
  const int tid = threadIdx.x;
  const int w = tid >> 6, l = tid & 63;
  const int wr = w >> 1, wc = w & 1;
  const int fq = l >> 4, fr = l & 15;
  const int m0 = blockIdx.x * 128;
  const int n0 = blockIdx.y * 128;

  __shared__ short lds[32768];       // 64 KB: staging dbuf; reused by epilogue
  short* sA0 = lds;
  short* sA1 = lds + 8192;
  short* sB0 = lds + 16384;
  short* sB1 = lds + 24576;

  f32x4 acc[4][4] = {};
  GEMM_KLOOP(A, W, m0, n0);
  __syncthreads();   // staging done; reuse LDS for epilogue

  short* sE = lds;
  const int part = n0 >> 10;          // 0=Q 1=K 2=V
  const int b = m0 >> 11, tloc = m0 & 2047;

  if (part < 2) {
    const float sc = part ? 1.0f : QSCALE;
#pragma unroll
    for (int m = 0; m < 4; ++m)
#pragma unroll
      for (int n = 0; n < 4; ++n)
#pragma unroll
        for (int j = 0; j < 4; ++j)
          sE[(wr * 64 + m * 16 + fq * 4 + j) * 136 + wc * 64 + n * 16 + fr] =
              f2bf(acc[m][n][j] * sc);
    __syncthreads();
    short* dst = part ? Kb : Qb;
    const int h0 = (n0 & 1023) >> 6;
#pragma unroll
    for (int v = 0; v < 8; ++v) {
      int vid = v * 256 + tid;
      int row = vid >> 4, seg = vid & 15;
      short8 val = *(const short8*)&sE[row * 136 + seg * 8];
      int h = h0 + (seg >> 3), dh0 = (seg & 7) * 8;
      *(short8*)&dst[(((size_t)(b * NH + h) * T_ + tloc + row)) * DH + dh0] = val;
    }
  } else {
#pragma unroll
    for (int m = 0; m < 4; ++m)
#pragma unroll
      for (int n = 0; n < 4; ++n) {
        uint2v pk;
        pk[0] = cvtpk(acc[m][n][0], acc[m][n][1]);
        pk[1] = cvtpk(acc[m][n][2], acc[m][n][3]);
        *(uint2v*)&sE[(wc * 64 + n * 16 + fr) * 136 + wr * 64 + m * 16 + fq * 4] = pk;
      }
    __syncthreads();
    const int h0 = (n0 & 1023) >> 6;
#pragma unroll
    for (int v = 0; v < 8; ++v) {
      int vid = v * 256 + tid;
      int col = vid >> 4, seg = vid & 15;
      short8 val = *(const short8*)&sE[col * 136 + seg * 8];
      int h = h0 + (col >> 6), dh = col & 63;
      *(short8*)&Vtb[(((size_t)(b * NH + h) * DH + dh)) * T_ + tloc + seg * 8] = val;
    }
  }
}

// ---------------- proj GEMM: out[m][n] = sum_k O[m][k]*Wp[n][k] (fp32 out) ----------------
__global__ __launch_bounds__(256, 2) void k_gemm_proj(
    const short* __restrict__ A,    // [M_, DM] bf16 (attention out)
    const short* __restrict__ W,    // [DM, DM] bf16
    float* __restrict__ C) {
  const int tid = threadIdx.x;
  const int w = tid >> 6, l = tid & 63;
  const int wr = w >> 1, wc = w & 1;
  const int fq = l >> 4, fr = l & 15;
  const int m0 = blockIdx.x * 128;
  const int n0 = blockIdx.y * 128;

  __shared__ short lds[32768];
  short* sA0 = lds;
  short* sA1 = lds + 8192;
  short* sB0 = lds + 16384;
  short* sB1 = lds + 24576;

  f32x4 acc[4][4] = {};
  GEMM_KLOOP(A, W, m0, n0);

#pragma unroll
  for (int m = 0; m < 4; ++m) {
    int row0 = m0 + wr * 64 + m * 16 + fq * 4;
#pragma unroll
    for (int n = 0; n < 4; ++n) {
      int col = n0 + wc * 64 + n * 16 + fr;
#pragma unroll
      for (int j = 0; j < 4; ++j)
        C[(size_t)(row0 + j) * DM + col] = acc[m][n][j];
    }
  }
}

// ---------------- flash attention v10: KVBLK=128 (half the stage/barrier boundaries) ----
// Same equal-work schedule as v9, in 128-row K/V units: per bh 72 units = 8 x 9.
// even u: qtA kt 0..9; odd u: qtA kt 9..2qtA+2, then whole qtB. CSUB2 stays at
// 64-row granularity (called twice per iteration, compile-time LDS offsets) ->
// register pressure unchanged, barrier/vmcnt overhead per staged byte halves.
// LDS 64 KB/block -> 2 blocks/CU; grid 512 fully co-resident; bh XCD-pinned.
__global__ __launch_bounds__(256, 2) void k_attn10(
    const short* __restrict__ Qb,   // [bh][t][dh], pre-scaled
    const short* __restrict__ Kb,   // [bh][t][dh]
    const short* __restrict__ Vtb,  // [bh][dh][t]
    short* __restrict__ Ob,         // [b][t][h*64+d] bf16
    unsigned* __restrict__ Pbuf,    // [512 pid][8192] dwords: fragment-layout partials
    float* __restrict__ Lbuf) {     // [512 pid][256] f32 lsums
  const int tid = threadIdx.x;
  const int w = tid >> 6, l = tid & 63;
  const int lq = l & 31, hi = l >> 5;
  const int id = blockIdx.x;
  const int x = id >> 6;
  const int u = (x < 4) ? (2 * x) : (2 * (x - 4) + 1);
  const int bh = id & 63;           // id%8 = bh%8 -> bh pinned to one XCD
  const int qtA = 7 - (u >> 1);
  const int b = bh >> 4, h = bh & 15;

  __shared__ short lds[32768];  // sK dbuf [2][8192] | sVt dbuf [2][8192]; epi reuse
  short* sK = lds;
  short* sVt = lds + 16384;

  // kt in 128-row units; each half (64 rows) stored as its own [64][64] subtile.
  auto STAGE = [&](int buf, int kt) {
#pragma unroll
    for (int ht = 0; ht < 2; ++ht)
#pragma unroll
      for (int i = 0; i < 2; ++i) {
        int lin = i * 256 + tid;
        int row = lin >> 3, pseg = lin & 7;
        int gseg = pseg ^ (row & 7);
        gload_lds16(&Kb[((size_t)bh * T_ + kt * 128 + ht * 64 + row) * DH + gseg * 8],
                    &sK[buf * 8192 + ht * 4096 + lin * 8]);
      }
#pragma unroll
    for (int ht = 0; ht < 2; ++ht)
#pragma unroll
      for (int i = 0; i < 2; ++i) {
        int lin = i * 256 + tid;
        int row = lin >> 3, pseg = lin & 7;
        int gseg = pseg ^ (row & 7);
        gload_lds16(&Vtb[((size_t)bh * DH + row) * T_ + kt * 128 + ht * 64 + gseg * 8],
                    &sVt[buf * 8192 + ht * 4096 + lin * 8]);
      }
  };

  auto SMAX = [&](int t64, int q0s, f32x16& sa, f32x16& sb, float& lsum, short8 (&pb)[4]) {
    if (t64 * 64 + 63 > q0s) {
      const int qg = q0s + lq;
#pragma unroll
      for (int r = 0; r < 16; ++r) {
        int kg0 = t64 * 64 + (r & 3) + 8 * (r >> 2) + 4 * hi;
        if (kg0 > qg) sa[r] = -1e30f;
        if (kg0 + 32 > qg) sb[r] = -1e30f;
      }
    }
#pragma unroll
    for (int r = 0; r < 16; ++r) {
      sa[r] = expasm(sa[r]);
      sb[r] = expasm(sb[r]);
    }
    {
      float t[8];
#pragma unroll
      for (int i = 0; i < 8; ++i)
        t[i] = (sa[2 * i] + sa[2 * i + 1]) + (sb[2 * i] + sb[2 * i + 1]);
      float u0 = (t[0] + t[1]) + (t[2] + t[3]);
      float u1 = (t[4] + t[5]) + (t[6] + t[7]);
      lsum += u0 + u1;
    }
#pragma unroll
    for (int st = 0; st < 2; ++st) {
      const f32x16& P = st ? sb : sa;
      unsigned x0 = cvtpk(P[0], P[1]);
      unsigned x1 = cvtpk(P[2], P[3]);
      unsigned y0 = cvtpk(P[4], P[5]);
      unsigned y1 = cvtpk(P[6], P[7]);
      uint2v r0 = __builtin_amdgcn_permlane32_swap(x0, y0, false, false);
      uint2v r1 = __builtin_amdgcn_permlane32_swap(x1, y1, false, false);
      unsigned x2 = cvtpk(P[8], P[9]);
      unsigned x3 = cvtpk(P[10], P[11]);
      unsigned y2 = cvtpk(P[12], P[13]);
      unsigned y3 = cvtpk(P[14], P[15]);
      uint2v r2 = __builtin_amdgcn_permlane32_swap(x2, y2, false, false);
      uint2v r3 = __builtin_amdgcn_permlane32_swap(x3, y3, false, false);
      uint4v ta, tb;
      ta[0] = r0[0]; ta[1] = r1[0]; ta[2] = r0[1]; ta[3] = r1[1];
      tb[0] = r2[0]; tb[1] = r3[0]; tb[2] = r2[1]; tb[3] = r3[1];
      pb[st * 2 + 0] = __builtin_bit_cast(short8, ta);
      pb[st * 2 + 1] = __builtin_bit_cast(short8, tb);
    }
  };

  auto RUN_SEG = [&](int qt, int k0, int k1, int ppid) {   // k0/k1 in 128-units
    const int q00 = qt * 256 + w * 32;
    const int q01 = q00 + 128;
    short8 qf0[4], qf1[4];
#pragma unroll
    for (int c = 0; c < 4; ++c) {
      qf0[c] = *(const short8*)&Qb[((size_t)bh * T_ + q00 + lq) * DH + c * 16 + hi * 8];
      qf1[c] = *(const short8*)&Qb[((size_t)bh * T_ + q01 + lq) * DH + c * 16 + hi * 8];
    }
    float ls0 = 0.f, ls1 = 0.f;
    f32x16 oa0[2] = {}, oa1[2] = {};

    // 64-row-granularity compute; t64 = global 64-subtile index, koff = LDS offset
    auto CSUB2 = [&](int t64, const int koff) {
      const bool do0 = (t64 * 64 <= q00 + 31);
      const bool do1 = (t64 * 64 <= q01 + 31);
      if (!do0 && !do1) return;
      f32x16 s0a = {}, s0b = {}, s1a = {}, s1b = {};
      __builtin_amdgcn_s_setprio(1);
#pragma unroll
      for (int st = 0; st < 2; ++st) {
        short8 kf[4];
#pragma unroll
        for (int c = 0; c < 4; ++c)
          kf[c] = *(const short8*)&sK[koff + (st * 32 + lq) * 64 +
                                      (((2 * c + hi) ^ (lq & 7)) * 8)];
        f32x16& d0 = st ? s0b : s0a;
        f32x16& d1 = st ? s1b : s1a;
#pragma unroll
        for (int c = 0; c < 4; ++c) {
          if (do0) d0 = __builtin_amdgcn_mfma_f32_32x32x16_bf16(kf[c], qf0[c], d0, 0, 0, 0);
          if (do1) d1 = __builtin_amdgcn_mfma_f32_32x32x16_bf16(kf[c], qf1[c], d1, 0, 0, 0);
        }
      }
      __builtin_amdgcn_s_setprio(0);

      short8 pb0[4], pb1[4];
      if (do0) SMAX(t64, q00, s0a, s0b, ls0, pb0);
      if (do1) SMAX(t64, q01, s1a, s1b, ls1, pb1);

      __builtin_amdgcn_s_setprio(1);
#pragma unroll
      for (int dt = 0; dt < 2; ++dt) {
        short8 vf[4];
#pragma unroll
        for (int c = 0; c < 4; ++c)
          vf[c] = *(const short8*)&sVt[koff + (dt * 32 + lq) * 64 +
                                       (((2 * c + hi) ^ (lq & 7)) * 8)];
#pragma unroll
        for (int c = 0; c < 4; ++c) {
          if (do0) oa0[dt] = __builtin_amdgcn_mfma_f32_32x32x16_bf16(vf[c], pb0[c], oa0[dt], 0, 0, 0);
          if (do1) oa1[dt] = __builtin_amdgcn_mfma_f32_32x32x16_bf16(vf[c], pb1[c], oa1[dt], 0, 0, 0);
        }
      }
      __builtin_amdgcn_s_setprio(0);
    };

    STAGE(0, k0);
    int t = k0;
    while (true) {
      if (t + 1 < k1) {
        STAGE(1, t + 1);
        asm volatile("s_waitcnt vmcnt(8)" ::: "memory");
      } else {
        asm volatile("s_waitcnt vmcnt(0)" ::: "memory");
      }
      __builtin_amdgcn_s_barrier();
      __builtin_amdgcn_sched_barrier(0);
      CSUB2(2 * t, 0);
      CSUB2(2 * t + 1, 4096);
      __builtin_amdgcn_s_barrier();
      if (++t == k1) break;

      if (t + 1 < k1) {
        STAGE(0, t + 1);
        asm volatile("s_waitcnt vmcnt(8)" ::: "memory");
      } else {
        asm volatile("s_waitcnt vmcnt(0)" ::: "memory");
      }
      __builtin_amdgcn_s_barrier();
      __builtin_amdgcn_sched_barrier(0);
      CSUB2(2 * t, 8192);
      CSUB2(2 * t + 1, 12288);
      __builtin_amdgcn_s_barrier();
      if (++t == k1) break;
    }

    ls0 += __shfl_xor(ls0, 32);
    ls1 += __shfl_xor(ls1, 32);

    if (ppid >= 0) {
      unsigned* Pb = Pbuf + (size_t)ppid * 8192;
#pragma unroll
      for (int sub = 0; sub < 2; ++sub) {
        const f32x16* OA = sub ? oa1 : oa0;
#pragma unroll
        for (int dt = 0; dt < 2; ++dt)
#pragma unroll
          for (int p = 0; p < 8; ++p)
            Pb[(((sub * 4 + w) * 2 + dt) * 8 + p) * 64 + l] =
                cvtpk(OA[dt][2 * p], OA[dt][2 * p + 1]);
      }
      if (hi == 0) {
        Lbuf[ppid * 256 + (0 * 4 + w) * 32 + lq] = ls0;
        Lbuf[ppid * 256 + (1 * 4 + w) * 32 + lq] = ls1;
      }
    } else {
      __syncthreads();
      short* sO = lds + w * 2304;  // [32][72] padded, wave-private
      const int qr = l >> 1, hf = l & 1;
      {
        float inv = 1.0f / ls0;
#pragma unroll
        for (int dt = 0; dt < 2; ++dt)
#pragma unroll
          for (int r = 0; r < 16; r += 2) {
            int dl = dt * 32 + (r & 3) + 8 * (r >> 2) + 4 * hi;
            *(unsigned*)&sO[lq * 72 + dl] = cvtpk(oa0[dt][r] * inv, oa0[dt][r + 1] * inv);
          }
        asm volatile("s_waitcnt lgkmcnt(0)" ::: "memory");
        __builtin_amdgcn_sched_barrier(0);
        const int tg = qt * 256 + w * 32 + qr;
#pragma unroll
        for (int ss = 0; ss < 4; ++ss) {
          short8 v = *(const short8*)&sO[qr * 72 + hf * 32 + ss * 8];
          *(short8*)&Ob[((size_t)(b * T_) + tg) * DM + h * 64 + hf * 32 + ss * 8] = v;
        }
        asm volatile("s_waitcnt lgkmcnt(0)" ::: "memory");
        __builtin_amdgcn_sched_barrier(0);
      }
      {
        float inv = 1.0f / ls1;
#pragma unroll
        for (int dt = 0; dt < 2; ++dt)
#pragma unroll
          for (int r = 0; r < 16; r += 2) {
            int dl = dt * 32 + (r & 3) + 8 * (r >> 2) + 4 * hi;
            *(unsigned*)&sO[lq * 72 + dl] = cvtpk(oa1[dt][r] * inv, oa1[dt][r + 1] * inv);
          }
        asm volatile("s_waitcnt lgkmcnt(0)" ::: "memory");
        __builtin_amdgcn_sched_barrier(0);
        const int tg = qt * 256 + 128 + w * 32 + qr;
#pragma unroll
        for (int ss = 0; ss < 4; ++ss) {
          short8 v = *(const short8*)&sO[qr * 72 + hf * 32 + ss * 8];
          *(short8*)&Ob[((size_t)(b * T_) + tg) * DM + h * 64 + hf * 32 + ss * 8] = v;
        }
      }
    }
  };

  if ((u & 1) == 0) {
    // first 9 128-tiles of qtA -> partial 0
    RUN_SEG(qtA, 0, 9, (bh * 4 + (qtA - 4)) * 2 + 0);
  } else {
    // tail of qtA -> partial 1, then whole small tile qtB -> direct
    RUN_SEG(qtA, 9, 2 * qtA + 2, (bh * 4 + (qtA - 4)) * 2 + 1);
    const int qtB = u >> 1;
    RUN_SEG(qtB, 0, 2 * qtB + 2, -1);
  }
}

// ---------------- merge: O = (P0 + P1) / (l0 + l1) for split q-tiles (qt 4..7) ----------------
__global__ __launch_bounds__(256) void k_merge(
    const unsigned* __restrict__ P, const float* __restrict__ L,
    short* __restrict__ Ob) {
  const int tid = threadIdx.x;
  const int w = tid >> 6, l = tid & 63;
  const int lq = l & 31, hi = l >> 5;
  const int sid = blockIdx.x;          // 256 = 4 qtm x 64 bh
  const int bh = sid & 63, qtm = sid >> 6;
  const int qt = 4 + qtm;
  const int b = bh >> 4, h = bh & 15;
  const int pid0 = (bh * 4 + qtm) * 2;
  const unsigned* P0 = P + (size_t)pid0 * 8192;
  const unsigned* P1 = P0 + 8192;

  __shared__ short sOm[9216];
  short* sO = sOm + w * 2304;          // wave-private [32][72]
  const int qr = l >> 1, hf = l & 1;

#pragma unroll
  for (int sub = 0; sub < 2; ++sub) {
    float l0 = L[pid0 * 256 + (sub * 4 + w) * 32 + lq];
    float l1 = L[(pid0 + 1) * 256 + (sub * 4 + w) * 32 + lq];
    float inv = 1.0f / (l0 + l1);
#pragma unroll
    for (int dt = 0; dt < 2; ++dt)
#pragma unroll
      for (int p = 0; p < 8; ++p) {
        int idx = (((sub * 4 + w) * 2 + dt) * 8 + p) * 64 + l;
        unsigned u0 = P0[idx], u1 = P1[idx];
        float e0 = bf2f((short)(u0 & 0xffff)) + bf2f((short)(u1 & 0xffff));
        float e1 = bf2f((short)(u0 >> 16)) + bf2f((short)(u1 >> 16));
        int r = 2 * p;
        int dl = dt * 32 + (r & 3) + 8 * (r >> 2) + 4 * hi;
        *(unsigned*)&sO[lq * 72 + dl] = cvtpk(e0 * inv, e1 * inv);
      }
    asm volatile("s_waitcnt lgkmcnt(0)" ::: "memory");
    __builtin_amdgcn_sched_barrier(0);
    const int tg = qt * 256 + sub * 128 + w * 32 + qr;
#pragma unroll
    for (int ss = 0; ss < 4; ++ss) {
      short8 v = *(const short8*)&sO[qr * 72 + hf * 32 + ss * 8];
      *(short8*)&Ob[((size_t)(b * T_) + tg) * DM + h * 64 + hf * 32 + ss * 8] = v;
    }
    asm volatile("s_waitcnt lgkmcnt(0)" ::: "memory");
    __builtin_amdgcn_sched_barrier(0);
  }
}

extern "C" void kernel_launch(void* const* d_in, const int* in_sizes, int n_in,
                              void* d_out, int out_size, void* d_ws, size_t ws_size,
                              hipStream_t stream) {
  const float* x     = (const float*)d_in[0];   // [4,2048,1024]
  const float* Wqkv  = (const float*)d_in[1];   // [3072,1024]
  const float* Wproj = (const float*)d_in[2];   // [1024,1024]
  float* out = (float*)d_out;

  short* ws = (short*)d_ws;
  short* xbf   = ws;                                  // 8192*1024 (dead after qkv GEMM)
  short* wqkvb = xbf + (size_t)M_ * DM;               // 3072*1024 (dead after qkv GEMM)
  short* wprjb = wqkvb + (size_t)3 * DM * DM;         // 1024*1024
  short* Qb    = wprjb + (size_t)DM * DM;             // pre-scaled by QSCALE
  short* Kb    = Qb + (size_t)BH * T_ * DH;
  short* Vtb   = Kb + (size_t)BH * T_ * DH;           // transposed [bh][dh][t]
  short* Ob    = Vtb + (size_t)BH * T_ * DH;          // 8192*1024
  unsigned* Pbuf = (unsigned*)xbf;                    // 512 pid x 8192 dwords
  float* Lbuf    = (float*)wqkvb;                     // 512 x 256 f32

  const int ncv = (M_ * DM + 3 * DM * DM + DM * DM) / 4;
  k_cvt3<<<(ncv + 255) / 256, 256, 0, stream>>>(
      (const float4*)x, (const float4*)Wqkv, (const float4*)Wproj,
      (ushort4*)xbf, (ushort4*)wqkvb, (ushort4*)wprjb);

  k_gemm_qkv<<<dim3(M_ / 128, 3 * DM / 128), 256, 0, stream>>>(xbf, wqkvb, Qb, Kb, Vtb);
  k_attn10<<<512, 256, 0, stream>>>(Qb, Kb, Vtb, Ob, Pbuf, Lbuf);
  k_merge<<<256, 256, 0, stream>>>(Pbuf, Lbuf, Ob);
  k_gemm_proj<<<dim3(M_ / 128, DM / 128), 256, 0, stream>>>(Ob, wprjb, out);
}

// Round 13
// 136.041 us; speedup vs baseline: 1.2228x; 1.2228x over previous
//
#include <hip/hip_runtime.h>
#include <hip/hip_bf16.h>
#include <math.h>

typedef __attribute__((ext_vector_type(8))) short short8;
typedef __attribute__((ext_vector_type(4))) float f32x4;
typedef __attribute__((ext_vector_type(16))) float f32x16;
typedef __attribute__((ext_vector_type(2))) unsigned uint2v;
typedef __attribute__((ext_vector_type(4))) unsigned uint4v;

#define B_  4
#define T_  2048
#define DM  1024
#define NH  16
#define DH  64
#define BH  (B_*NH)   // 64
#define M_  (B_*T_)   // 8192

// 1/sqrt(64) * log2(e): folded into Q at QKV-GEMM epilogue so attention scores
// come out of MFMA already in exp2-ready units.
#define QSCALE 0.18033688011112042f

static __device__ __forceinline__ short f2bf(float f) {
  unsigned u = __float_as_uint(f);
  unsigned r = (u + 0x7fff + ((u >> 16) & 1)) >> 16;
  return (short)r;
}

static __device__ __forceinline__ unsigned cvtpk(float lo, float hi) {
  unsigned r;
  asm("v_cvt_pk_bf16_f32 %0, %1, %2" : "=v"(r) : "v"(lo), "v"(hi));
  return r;
}

static __device__ __forceinline__ float expasm(float x) {
  float r;
  asm("v_exp_f32 %0, %1" : "=v"(r) : "v"(x));
  return r;
}

static __device__ __forceinline__ void gload_lds16(const void* g, void* l) {
  __builtin_amdgcn_global_load_lds((const __attribute__((address_space(1))) void*)g,
                                   (__attribute__((address_space(3))) void*)l, 16, 0, 0);
}

// ---------------- fp32 -> bf16 convert, all three tensors in one launch ----------------
__global__ void k_cvt3(const float4* __restrict__ x, const float4* __restrict__ wq,
                       const float4* __restrict__ wp, ushort4* __restrict__ ox,
                       ushort4* __restrict__ oq, ushort4* __restrict__ op) {
  const int n1 = M_ * DM / 4, n2 = 3 * DM * DM / 4, n3 = DM * DM / 4;
  int i = blockIdx.x * 256 + threadIdx.x;
  const float4* src;
  ushort4* dst;
  int j = i;
  if (i < n1) { src = x; dst = ox; }
  else if (i < n1 + n2) { src = wq; dst = oq; j = i - n1; }
  else if (i < n1 + n2 + n3) { src = wp; dst = op; j = i - n1 - n2; }
  else return;
  float4 v = src[j];
  ushort4 o;
  o.x = (ushort)f2bf(v.x); o.y = (ushort)f2bf(v.y);
  o.z = (ushort)f2bf(v.z); o.w = (ushort)f2bf(v.w);
  dst[j] = o;
}

// ================= GEMM core macros (128x128 tile, BK=64, dbuf, swizzled) =================
#define GEMM_STAGE(SRCA, SRCB, dA, dB, m0_, n0_, k0_)                          \
  {                                                                            \
    _Pragma("unroll")                                                          \
    for (int i = 0; i < 4; ++i) {                                              \
      int lin = i * 256 + tid;                                                 \
      int row = lin >> 3, pseg = lin & 7;                                      \
      int gseg = pseg ^ (row & 7);                                             \
      gload_lds16(&SRCA[(size_t)((m0_) + row) * DM + (k0_) + gseg * 8],        \
                  &(dA)[lin * 8]);                                             \
    }                                                                          \
    _Pragma("unroll")                                                          \
    for (int i = 0; i < 4; ++i) {                                              \
      int lin = i * 256 + tid;                                                 \
      int row = lin >> 3, pseg = lin & 7;                                      \
      int gseg = pseg ^ (row & 7);                                             \
      gload_lds16(&SRCB[(size_t)((n0_) + row) * DM + (k0_) + gseg * 8],        \
                  &(dB)[lin * 8]);                                             \
    }                                                                          \
  }

#define GEMM_COMPUTE(pA, pB)                                                   \
  {                                                                            \
    _Pragma("unroll")                                                          \
    for (int kk = 0; kk < 2; ++kk) {                                           \
      short8 aF[4], bF[4];                                                     \
      _Pragma("unroll")                                                        \
      for (int m = 0; m < 4; ++m)                                              \
        aF[m] = *(const short8*)&(pA)[(wr * 64 + m * 16 + fr) * 64 +           \
                                      (((kk * 4 + fq) ^ (fr & 7)) * 8)];       \
      _Pragma("unroll")                                                        \
      for (int n = 0; n < 4; ++n)                                              \
        bF[n] = *(const short8*)&(pB)[(wc * 64 + n * 16 + fr) * 64 +           \
                                      (((kk * 4 + fq) ^ (fr & 7)) * 8)];       \
      __builtin_amdgcn_s_setprio(1);                                           \
      _Pragma("unroll")                                                        \
      for (int m = 0; m < 4; ++m)                                              \
        _Pragma("unroll")                                                      \
        for (int n = 0; n < 4; ++n)                                            \
          acc[m][n] = __builtin_amdgcn_mfma_f32_16x16x32_bf16(aF[m], bF[n],    \
                                                              acc[m][n], 0, 0, 0); \
      __builtin_amdgcn_s_setprio(0);                                           \
    }                                                                          \
  }

#define GEMM_KLOOP(SRCA, SRCB, m0_, n0_)                                       \
  GEMM_STAGE(SRCA, SRCB, sA0, sB0, m0_, n0_, 0);                               \
  {                                                                            \
    _Pragma("unroll 1")                                                        \
    for (int t = 0; t < 16; ++t) {                                             \
      short* pA = (t & 1) ? sA1 : sA0;                                         \
      short* pB = (t & 1) ? sB1 : sB0;                                         \
      if (t < 15) {                                                            \
        short* nA = (t & 1) ? sA0 : sA1;                                       \
        short* nB = (t & 1) ? sB0 : sB1;                                       \
        GEMM_STAGE(SRCA, SRCB, nA, nB, m0_, n0_, (t + 1) * 64);                \
        asm volatile("s_waitcnt vmcnt(8)" ::: "memory");                       \
      } else {                                                                 \
        asm volatile("s_waitcnt vmcnt(0)" ::: "memory");                       \
      }                                                                        \
      __builtin_amdgcn_s_barrier();                                            \
      __builtin_amdgcn_sched_barrier(0);                                       \
      GEMM_COMPUTE(pA, pB);                                                    \
      asm volatile("" ::: "memory");                                           \
      __builtin_amdgcn_s_barrier();                                            \
    }                                                                          \
  }

// ---------------- QKV GEMM ----------------
// Q (scaled by QSCALE), K -> [bh][t][dh]; V -> transposed [bh][dh][t].
__global__ __launch_bounds__(256, 2) void k_gemm_qkv(
    const short* __restrict__ A,    // [M_, DM]
    const short* __restrict__ W,    // [3*DM, DM]
    short* __restrict__ Qb, short* __restrict__ Kb, short* __restrict__ Vtb) {
  const int tid = threadIdx.x;
  const int w = tid >> 6, l = tid & 63;
  const int wr = w >> 1, wc = w & 1;
  const int fq = l >> 4, fr = l & 15;
  const int m0 = blockIdx.x * 128;
  const int n0 = blockIdx.y * 128;

  __shared__ short lds[32768];       // 64 KB: staging dbuf; reused by epilogue
  short* sA0 = lds;
  short* sA1 = lds + 8192;
  short* sB0 = lds + 16384;
  short* sB1 = lds + 24576;

  f32x4 acc[4][4] = {};
  GEMM_KLOOP(A, W, m0, n0);
  __syncthreads();   // staging done; reuse LDS for epilogue

  short* sE = lds;
  const int part = n0 >> 10;          // 0=Q 1=K 2=V
  const int b = m0 >> 11, tloc = m0 & 2047;

  if (part < 2) {
    const float sc = part ? 1.0f : QSCALE;
#pragma unroll
    for (int m = 0; m < 4; ++m)
#pragma unroll
      for (int n = 0; n < 4; ++n)
#pragma unroll
        for (int j = 0; j < 4; ++j)
          sE[(wr * 64 + m * 16 + fq * 4 + j) * 136 + wc * 64 + n * 16 + fr] =
              f2bf(acc[m][n][j] * sc);
    __syncthreads();
    short* dst = part ? Kb : Qb;
    const int h0 = (n0 & 1023) >> 6;
#pragma unroll
    for (int v = 0; v < 8; ++v) {
      int vid = v * 256 + tid;
      int row = vid >> 4, seg = vid & 15;
      short8 val = *(const short8*)&sE[row * 136 + seg * 8];
      int h = h0 + (seg >> 3), dh0 = (seg & 7) * 8;
      *(short8*)&dst[(((size_t)(b * NH + h) * T_ + tloc + row)) * DH + dh0] = val;
    }
  } else {
#pragma unroll
    for (int m = 0; m < 4; ++m)
#pragma unroll
      for (int n = 0; n < 4; ++n) {
        uint2v pk;
        pk[0] = cvtpk(acc[m][n][0], acc[m][n][1]);
        pk[1] = cvtpk(acc[m][n][2], acc[m][n][3]);
        *(uint2v*)&sE[(wc * 64 + n * 16 + fr) * 136 + wr * 64 + m * 16 + fq * 4] = pk;
      }
    __syncthreads();
    const int h0 = (n0 & 1023) >> 6;
#pragma unroll
    for (int v = 0; v < 8; ++v) {
      int vid = v * 256 + tid;
      int col = vid >> 4, seg = vid & 15;
      short8 val = *(const short8*)&sE[col * 136 + seg * 8];
      int h = h0 + (col >> 6), dh = col & 63;
      *(short8*)&Vtb[(((size_t)(b * NH + h) * DH + dh)) * T_ + tloc + seg * 8] = val;
    }
  }
}

// ---------------- proj GEMM: out[m][n] = sum_k O[m][k]*Wp[n][k] (fp32 out) ----------------
__global__ __launch_bounds__(256, 2) void k_gemm_proj(
    const short* __restrict__ A,    // [M_, DM] bf16 (attention out)
    const short* __restrict__ W,    // [DM, DM] bf16
    float* __restrict__ C) {
  const int tid = threadIdx.x;
  const int w = tid >> 6, l = tid & 63;
  const int wr = w >> 1, wc = w & 1;
  const int fq = l >> 4, fr = l & 15;
  const int m0 = blockIdx.x * 128;
  const int n0 = blockIdx.y * 128;

  __shared__ short lds[32768];
  short* sA0 = lds;
  short* sA1 = lds + 8192;
  short* sB0 = lds + 16384;
  short* sB1 = lds + 24576;

  f32x4 acc[4][4] = {};
  GEMM_KLOOP(A, W, m0, n0);

#pragma unroll
  for (int m = 0; m < 4; ++m) {
    int row0 = m0 + wr * 64 + m * 16 + fq * 4;
#pragma unroll
    for (int n = 0; n < 4; ++n) {
      int col = n0 + wc * 64 + n * 16 + fr;
#pragma unroll
      for (int j = 0; j < 4; ++j)
        C[(size_t)(row0 + j) * DM + col] = acc[m][n][j];
    }
  }
}

// ---------------- flash attention v11: 8 waves x 1 sub-tile (TLP over ILP) ----------------
// Grid 512 = 8 units x 64 bh, block = 512 threads (8 waves x 32 q-rows = 256 rows).
// Same CU-pair schedule as v7 (qt = x<4 ? 7-x : x-4; ids id,id+256 share a CU ->
// per-CU work exactly 36 tiles). 4 waves/SIMD: wave-level overlap of MFMA, softmax
// VALU, and ds_read across the same barriers. Static softmax (Q pre-scaled).
__global__ __launch_bounds__(512, 4) void k_attn11(
    const short* __restrict__ Qb,   // [bh][t][dh], pre-scaled
    const short* __restrict__ Kb,   // [bh][t][dh]
    const short* __restrict__ Vtb,  // [bh][dh][t]
    short* __restrict__ Ob) {       // [b][t][h*64+d] bf16
  const int tid = threadIdx.x;
  const int w = tid >> 6, l = tid & 63;
  const int lq = l & 31, hi = l >> 5;
  const int id = blockIdx.x;
  const int x = id >> 6;
  const int qt = (x < 4) ? (7 - x) : (x - 4);
  const int bh = id & 63;           // id%8 = bh%8 -> bh pinned to one XCD
  const int b = bh >> 4, h = bh & 15;

  __shared__ short lds[18432];  // staging: sK[2][4096] | sVt[2][4096]; epi: 8x[32][72]
  short* sK = lds;
  short* sVt = lds + 8192;

  // 512 threads: each stages one 8-short chunk of K and one of V.
  auto STAGE = [&](int buf, int kt) {
    int row = tid >> 3, pseg = tid & 7;
    int gseg = pseg ^ (row & 7);
    gload_lds16(&Kb[((size_t)bh * T_ + kt * 64 + row) * DH + gseg * 8],
                &sK[buf * 4096 + tid * 8]);
    gload_lds16(&Vtb[((size_t)bh * DH + row) * T_ + kt * 64 + gseg * 8],
                &sVt[buf * 4096 + tid * 8]);
  };

  const int nkt = 4 * qt + 4;
  const int q0 = qt * 256 + w * 32;    // this wave's 32 q-rows
  const int qg = q0 + lq;

  short8 qf[4];
#pragma unroll
  for (int c = 0; c < 4; ++c)
    qf[c] = *(const short8*)&Qb[((size_t)bh * T_ + qg) * DH + c * 16 + hi * 8];
  asm volatile("s_waitcnt vmcnt(0)" ::: "memory");

  float lsum = 0.f;
  f32x16 oacc[2] = {};

  auto CSUB = [&](int kt, const int koff) {
    // ---- S^T = K · Q^T (scores already in exp2 units) ----
    f32x16 a0 = {}, a1 = {};
    __builtin_amdgcn_s_setprio(1);
#pragma unroll
    for (int c = 0; c < 4; ++c) {
      short8 kf0 = *(const short8*)&sK[koff + (lq) * 64 + (((2 * c + hi) ^ (lq & 7)) * 8)];
      short8 kf1 = *(const short8*)&sK[koff + (32 + lq) * 64 + (((2 * c + hi) ^ (lq & 7)) * 8)];
      a0 = __builtin_amdgcn_mfma_f32_32x32x16_bf16(kf0, qf[c], a0, 0, 0, 0);
      a1 = __builtin_amdgcn_mfma_f32_32x32x16_bf16(kf1, qf[c], a1, 0, 0, 0);
    }
    __builtin_amdgcn_s_setprio(0);

    // ---- causal mask (diagonal-crossing tiles only) ----
    if (kt * 64 + 63 > q0) {
#pragma unroll
      for (int r = 0; r < 16; ++r) {
        int kg0 = kt * 64 + (r & 3) + 8 * (r >> 2) + 4 * hi;
        if (kg0 > qg) a0[r] = -1e30f;
        if (kg0 + 32 > qg) a1[r] = -1e30f;
      }
    }

    // ---- p = exp2(s) in place; tree-sum into lsum ----
#pragma unroll
    for (int r = 0; r < 16; ++r) {
      a0[r] = expasm(a0[r]);
      a1[r] = expasm(a1[r]);
    }
    {
      float t[8];
#pragma unroll
      for (int i = 0; i < 8; ++i)
        t[i] = (a0[2 * i] + a0[2 * i + 1]) + (a1[2 * i] + a1[2 * i + 1]);
      float u0 = (t[0] + t[1]) + (t[2] + t[3]);
      float u1 = (t[4] + t[5]) + (t[6] + t[7]);
      lsum += u0 + u1;
    }

    // ---- P -> bf16 B-fragments via cvt_pk + permlane32_swap (T12) ----
    short8 pb[4];
#pragma unroll
    for (int st = 0; st < 2; ++st) {
      const f32x16& P = st ? a1 : a0;
      unsigned x0 = cvtpk(P[0], P[1]);
      unsigned x1 = cvtpk(P[2], P[3]);
      unsigned y0 = cvtpk(P[4], P[5]);
      unsigned y1 = cvtpk(P[6], P[7]);
      uint2v r0 = __builtin_amdgcn_permlane32_swap(x0, y0, false, false);
      uint2v r1 = __builtin_amdgcn_permlane32_swap(x1, y1, false, false);
      unsigned x2 = cvtpk(P[8], P[9]);
      unsigned x3 = cvtpk(P[10], P[11]);
      unsigned y2 = cvtpk(P[12], P[13]);
      unsigned y3 = cvtpk(P[14], P[15]);
      uint2v r2 = __builtin_amdgcn_permlane32_swap(x2, y2, false, false);
      uint2v r3 = __builtin_amdgcn_permlane32_swap(x3, y3, false, false);
      uint4v ta, tb;
      ta[0] = r0[0]; ta[1] = r1[0]; ta[2] = r0[1]; ta[3] = r1[1];
      tb[0] = r2[0]; tb[1] = r3[0]; tb[2] = r2[1]; tb[3] = r3[1];
      pb[st * 2 + 0] = __builtin_bit_cast(short8, ta);
      pb[st * 2 + 1] = __builtin_bit_cast(short8, tb);
    }

    // ---- O^T += V^T · P ----
    __builtin_amdgcn_s_setprio(1);
#pragma unroll
    for (int dt = 0; dt < 2; ++dt) {
#pragma unroll
      for (int c = 0; c < 4; ++c) {
        short8 vf = *(const short8*)&sVt[koff + (dt * 32 + lq) * 64 +
                                         (((2 * c + hi) ^ (lq & 7)) * 8)];
        oacc[dt] = __builtin_amdgcn_mfma_f32_32x32x16_bf16(vf, pb[c], oacc[dt], 0, 0, 0);
      }
    }
    __builtin_amdgcn_s_setprio(0);
  };

  // ---- pipelined K/V loop, 2x-unrolled so buffer offsets are compile-time ----
  STAGE(0, 0);
  int t = 0;
  while (true) {
    if (t + 1 < nkt) {
      STAGE(1, t + 1);
      asm volatile("s_waitcnt vmcnt(2)" ::: "memory");
    } else {
      asm volatile("s_waitcnt vmcnt(0)" ::: "memory");
    }
    __builtin_amdgcn_s_barrier();
    __builtin_amdgcn_sched_barrier(0);
    if (t * 64 <= q0 + 31) CSUB(t, 0);
    __builtin_amdgcn_s_barrier();
    if (++t == nkt) break;

    if (t + 1 < nkt) {
      STAGE(0, t + 1);
      asm volatile("s_waitcnt vmcnt(2)" ::: "memory");
    } else {
      asm volatile("s_waitcnt vmcnt(0)" ::: "memory");
    }
    __builtin_amdgcn_s_barrier();
    __builtin_amdgcn_sched_barrier(0);
    if (t * 64 <= q0 + 31) CSUB(t, 4096);
    __builtin_amdgcn_s_barrier();
    if (++t == nkt) break;
  }

  // ---- epilogue: per-wave-private LDS transpose -> coalesced bf16 stores ----
  lsum += __shfl_xor(lsum, 32);
  __syncthreads();  // all waves done with staging buffers
  short* sO = lds + w * 2304;  // [32][72] padded, wave-private (8 x 2304 = 18432)
  float inv = 1.0f / lsum;
#pragma unroll
  for (int dt = 0; dt < 2; ++dt)
#pragma unroll
    for (int r = 0; r < 16; r += 2) {
      int dl = dt * 32 + (r & 3) + 8 * (r >> 2) + 4 * hi;
      *(unsigned*)&sO[lq * 72 + dl] = cvtpk(oacc[dt][r] * inv, oacc[dt][r + 1] * inv);
    }
  asm volatile("s_waitcnt lgkmcnt(0)" ::: "memory");
  __builtin_amdgcn_sched_barrier(0);
  {
    int qr = l >> 1, hf = l & 1;
    const int tg = q0 + qr;
#pragma unroll
    for (int ss = 0; ss < 4; ++ss) {
      short8 v = *(const short8*)&sO[qr * 72 + hf * 32 + ss * 8];
      *(short8*)&Ob[((size_t)(b * T_) + tg) * DM + h * 64 + hf * 32 + ss * 8] = v;
    }
  }
}

extern "C" void kernel_launch(void* const* d_in, const int* in_sizes, int n_in,
                              void* d_out, int out_size, void* d_ws, size_t ws_size,
                              hipStream_t stream) {
  const float* x     = (const float*)d_in[0];   // [4,2048,1024]
  const float* Wqkv  = (const float*)d_in[1];   // [3072,1024]
  const float* Wproj = (const float*)d_in[2];   // [1024,1024]
  float* out = (float*)d_out;

  short* ws = (short*)d_ws;
  short* xbf   = ws;                                  // 8192*1024
  short* wqkvb = xbf + (size_t)M_ * DM;               // 3072*1024
  short* wprjb = wqkvb + (size_t)3 * DM * DM;         // 1024*1024
  short* Qb    = wprjb + (size_t)DM * DM;             // pre-scaled by QSCALE
  short* Kb    = Qb + (size_t)BH * T_ * DH;
  short* Vtb   = Kb + (size_t)BH * T_ * DH;           // transposed [bh][dh][t]
  short* Ob    = Vtb + (size_t)BH * T_ * DH;          // 8192*1024

  const int ncv = (M_ * DM + 3 * DM * DM + DM * DM) / 4;
  k_cvt3<<<(ncv + 255) / 256, 256, 0, stream>>>(
      (const float4*)x, (const float4*)Wqkv, (const float4*)Wproj,
      (ushort4*)xbf, (ushort4*)wqkvb, (ushort4*)wprjb);

  k_gemm_qkv<<<dim3(M_ / 128, 3 * DM / 128), 256, 0, stream>>>(xbf, wqkvb, Qb, Kb, Vtb);
  k_attn11<<<512, 512, 0, stream>>>(Qb, Kb, Vtb, Ob);
  k_gemm_proj<<<dim3(M_ / 128, DM / 128), 256, 0, stream>>>(Ob, wprjb, out);
}

// Round 14
// 135.970 us; speedup vs baseline: 1.2234x; 1.0005x over previous
//
#include <hip/hip_runtime.h>
#include <hip/hip_bf16.h>
#include <math.h>

typedef __attribute__((ext_vector_type(8))) short short8;
typedef __attribute__((ext_vector_type(4))) float f32x4;
typedef __attribute__((ext_vector_type(16))) float f32x16;
typedef __attribute__((ext_vector_type(2))) unsigned uint2v;
typedef __attribute__((ext_vector_type(4))) unsigned uint4v;

#define B_  4
#define T_  2048
#define DM  1024
#define NH  16
#define DH  64
#define BH  (B_*NH)   // 64
#define M_  (B_*T_)   // 8192

// 1/sqrt(64) * log2(e): folded into Q at QKV-GEMM epilogue so attention scores
// come out of MFMA already in exp2-ready units.
#define QSCALE 0.18033688011112042f

static __device__ __forceinline__ short f2bf(float f) {
  unsigned u = __float_as_uint(f);
  unsigned r = (u + 0x7fff + ((u >> 16) & 1)) >> 16;
  return (short)r;
}

static __device__ __forceinline__ unsigned cvtpk(float lo, float hi) {
  unsigned r;
  asm("v_cvt_pk_bf16_f32 %0, %1, %2" : "=v"(r) : "v"(lo), "v"(hi));
  return r;
}

static __device__ __forceinline__ float expasm(float x) {
  float r;
  asm("v_exp_f32 %0, %1" : "=v"(r) : "v"(x));
  return r;
}

static __device__ __forceinline__ void gload_lds16(const void* g, void* l) {
  __builtin_amdgcn_global_load_lds((const __attribute__((address_space(1))) void*)g,
                                   (__attribute__((address_space(3))) void*)l, 16, 0, 0);
}

// ---------------- fp32 -> bf16 convert, all three tensors in one launch ----------------
__global__ void k_cvt3(const float4* __restrict__ x, const float4* __restrict__ wq,
                       const float4* __restrict__ wp, ushort4* __restrict__ ox,
                       ushort4* __restrict__ oq, ushort4* __restrict__ op) {
  const int n1 = M_ * DM / 4, n2 = 3 * DM * DM / 4, n3 = DM * DM / 4;
  int i = blockIdx.x * 256 + threadIdx.x;
  const float4* src;
  ushort4* dst;
  int j = i;
  if (i < n1) { src = x; dst = ox; }
  else if (i < n1 + n2) { src = wq; dst = oq; j = i - n1; }
  else if (i < n1 + n2 + n3) { src = wp; dst = op; j = i - n1 - n2; }
  else return;
  float4 v = src[j];
  ushort4 o;
  o.x = (ushort)f2bf(v.x); o.y = (ushort)f2bf(v.y);
  o.z = (ushort)f2bf(v.z); o.w = (ushort)f2bf(v.w);
  dst[j] = o;
}

// ================= GEMM core macros (128x128 tile, BK=64, dbuf, swizzled) =================
#define GEMM_STAGE(SRCA, SRCB, dA, dB, m0_, n0_, k0_)                          \
  {                                                                            \
    _Pragma("unroll")                                                          \
    for (int i = 0; i < 4; ++i) {                                              \
      int lin = i * 256 + tid;                                                 \
      int row = lin >> 3, pseg = lin & 7;                                      \
      int gseg = pseg ^ (row & 7);                                             \
      gload_lds16(&SRCA[(size_t)((m0_) + row) * DM + (k0_) + gseg * 8],        \
                  &(dA)[lin * 8]);                                             \
    }                                                                          \
    _Pragma("unroll")                                                          \
    for (int i = 0; i < 4; ++i) {                                              \
      int lin = i * 256 + tid;                                                 \
      int row = lin >> 3, pseg = lin & 7;                                      \
      int gseg = pseg ^ (row & 7);                                             \
      gload_lds16(&SRCB[(size_t)((n0_) + row) * DM + (k0_) + gseg * 8],        \
                  &(dB)[lin * 8]);                                             \
    }                                                                          \
  }

#define GEMM_COMPUTE(pA, pB)                                                   \
  {                                                                            \
    _Pragma("unroll")                                                          \
    for (int kk = 0; kk < 2; ++kk) {                                           \
      short8 aF[4], bF[4];                                                     \
      _Pragma("unroll")                                                        \
      for (int m = 0; m < 4; ++m)                                              \
        aF[m] = *(const short8*)&(pA)[(wr * 64 + m * 16 + fr) * 64 +           \
                                      (((kk * 4 + fq) ^ (fr & 7)) * 8)];       \
      _Pragma("unroll")                                                        \
      for (int n = 0; n < 4; ++n)                                              \
        bF[n] = *(const short8*)&(pB)[(wc * 64 + n * 16 + fr) * 64 +           \
                                      (((kk * 4 + fq) ^ (fr & 7)) * 8)];       \
      __builtin_amdgcn_s_setprio(1);                                           \
      _Pragma("unroll")                                                        \
      for (int m = 0; m < 4; ++m)                                              \
        _Pragma("unroll")                                                      \
        for (int n = 0; n < 4; ++n)                                            \
          acc[m][n] = __builtin_amdgcn_mfma_f32_16x16x32_bf16(aF[m], bF[n],    \
                                                              acc[m][n], 0, 0, 0); \
      __builtin_amdgcn_s_setprio(0);                                           \
    }                                                                          \
  }

#define GEMM_KLOOP(SRCA, SRCB, m0_, n0_)                                       \
  GEMM_STAGE(SRCA, SRCB, sA0, sB0, m0_, n0_, 0);                               \
  {                                                                            \
    _Pragma("unroll 1")                                                        \
    for (int t = 0; t < 16; ++t) {                                             \
      short* pA = (t & 1) ? sA1 : sA0;                                         \
      short* pB = (t & 1) ? sB1 : sB0;                                         \
      if (t < 15) {                                                            \
        short* nA = (t & 1) ? sA0 : sA1;                                       \
        short* nB = (t & 1) ? sB0 : sB1;                                       \
        GEMM_STAGE(SRCA, SRCB, nA, nB, m0_, n0_, (t + 1) * 64);                \
        asm volatile("s_waitcnt vmcnt(8)" ::: "memory");                       \
      } else {                                                                 \
        asm volatile("s_waitcnt vmcnt(0)" ::: "memory");                       \
      }                                                                        \
      __builtin_amdgcn_s_barrier();                                            \
      __builtin_amdgcn_sched_barrier(0);                                       \
      GEMM_COMPUTE(pA, pB);                                                    \
      asm volatile("" ::: "memory");                                           \
      __builtin_amdgcn_s_barrier();                                            \
    }                                                                          \
  }

// ---------------- QKV GEMM ----------------
// Q (scaled by QSCALE), K -> [bh][t][dh]; V -> transposed [bh][dh][t].
__global__ __launch_bounds__(256, 2) void k_gemm_qkv(
    const short* __restrict__ A,    // [M_, DM]
    const short* __restrict__ W,    // [3*DM, DM]
    short* __restrict__ Qb, short* __restrict__ Kb, short* __restrict__ Vtb) {
  const int tid = threadIdx.x;
  const int w = tid >> 6, l = tid & 63;
  const int wr = w >> 1, wc = w & 1;
  const int fq = l >> 4, fr = l & 15;
  const int m0 = blockIdx.x * 128;
  const int n0 = blockIdx.y * 128;

  __shared__ short lds[32768];       // 64 KB: staging dbuf; reused by epilogue
  short* sA0 = lds;
  short* sA1 = lds + 8192;
  short* sB0 = lds + 16384;
  short* sB1 = lds + 24576;

  f32x4 acc[4][4] = {};
  GEMM_KLOOP(A, W, m0, n0);
  __syncthreads();   // staging done; reuse LDS for epilogue

  short* sE = lds;
  const int part = n0 >> 10;          // 0=Q 1=K 2=V
  const int b = m0 >> 11, tloc = m0 & 2047;

  if (part < 2) {
    const float sc = part ? 1.0f : QSCALE;
#pragma unroll
    for (int m = 0; m < 4; ++m)
#pragma unroll
      for (int n = 0; n < 4; ++n)
#pragma unroll
        for (int j = 0; j < 4; ++j)
          sE[(wr * 64 + m * 16 + fq * 4 + j) * 136 + wc * 64 + n * 16 + fr] =
              f2bf(acc[m][n][j] * sc);
    __syncthreads();
    short* dst = part ? Kb : Qb;
    const int h0 = (n0 & 1023) >> 6;
#pragma unroll
    for (int v = 0; v < 8; ++v) {
      int vid = v * 256 + tid;
      int row = vid >> 4, seg = vid & 15;
      short8 val = *(const short8*)&sE[row * 136 + seg * 8];
      int h = h0 + (seg >> 3), dh0 = (seg & 7) * 8;
      *(short8*)&dst[(((size_t)(b * NH + h) * T_ + tloc + row)) * DH + dh0] = val;
    }
  } else {
#pragma unroll
    for (int m = 0; m < 4; ++m)
#pragma unroll
      for (int n = 0; n < 4; ++n) {
        uint2v pk;
        pk[0] = cvtpk(acc[m][n][0], acc[m][n][1]);
        pk[1] = cvtpk(acc[m][n][2], acc[m][n][3]);
        *(uint2v*)&sE[(wc * 64 + n * 16 + fr) * 136 + wr * 64 + m * 16 + fq * 4] = pk;
      }
    __syncthreads();
    const int h0 = (n0 & 1023) >> 6;
#pragma unroll
    for (int v = 0; v < 8; ++v) {
      int vid = v * 256 + tid;
      int col = vid >> 4, seg = vid & 15;
      short8 val = *(const short8*)&sE[col * 136 + seg * 8];
      int h = h0 + (col >> 6), dh = col & 63;
      *(short8*)&Vtb[(((size_t)(b * NH + h) * DH + dh)) * T_ + tloc + seg * 8] = val;
    }
  }
}

// ---------------- proj GEMM: out[m][n] = sum_k O[m][k]*Wp[n][k] (fp32 out) ----------------
__global__ __launch_bounds__(256, 2) void k_gemm_proj(
    const short* __restrict__ A,    // [M_, DM] bf16 (attention out)
    const short* __restrict__ W,    // [DM, DM] bf16
    float* __restrict__ C) {
  const int tid = threadIdx.x;
  const int w = tid >> 6, l = tid & 63;
  const int wr = w >> 1, wc = w & 1;
  const int fq = l >> 4, fr = l & 15;
  const int m0 = blockIdx.x * 128;
  const int n0 = blockIdx.y * 128;

  __shared__ short lds[32768];
  short* sA0 = lds;
  short* sA1 = lds + 8192;
  short* sB0 = lds + 16384;
  short* sB1 = lds + 24576;

  f32x4 acc[4][4] = {};
  GEMM_KLOOP(A, W, m0, n0);

#pragma unroll
  for (int m = 0; m < 4; ++m) {
    int row0 = m0 + wr * 64 + m * 16 + fq * 4;
#pragma unroll
    for (int n = 0; n < 4; ++n) {
      int col = n0 + wc * 64 + n * 16 + fr;
#pragma unroll
      for (int j = 0; j < 4; ++j)
        C[(size_t)(row0 + j) * DM + col] = acc[m][n][j];
    }
  }
}

// ---------------- flash attention v12: 4-slot ring, ONE barrier per tile ----------------
// attn11 structure (8 waves x 32 q-rows, TLP) + deeper pipeline: stage D=2 tiles
// ahead into a 4-slot ring (64 KB). Race-freedom: stage(t+2)@iter t targets slot
// (t+2)&3, last read by CSUB(t-2) which finished before barrier(t-1); the stage
// is issued after barrier(t-1) -> ordered. Data-ready: at barrier(t) outstanding
// stages = tiles t+1,t+2 (4 loads/thread) -> vmcnt(4) forces tile t landed.
// Counted vmcnt never drains until the 2-iteration tail. One s_barrier per tile.
__global__ __launch_bounds__(512, 4) void k_attn12(
    const short* __restrict__ Qb,   // [bh][t][dh], pre-scaled
    const short* __restrict__ Kb,   // [bh][t][dh]
    const short* __restrict__ Vtb,  // [bh][dh][t]
    short* __restrict__ Ob) {       // [b][t][h*64+d] bf16
  const int tid = threadIdx.x;
  const int w = tid >> 6, l = tid & 63;
  const int lq = l & 31, hi = l >> 5;
  const int id = blockIdx.x;
  const int x = id >> 6;
  const int qt = (x < 4) ? (7 - x) : (x - 4);
  const int bh = id & 63;           // id%8 = bh%8 -> bh pinned to one XCD
  const int b = bh >> 4, h = bh & 15;

  __shared__ short lds[32768];  // 4 slots x (K[64][64] | V^T[64][64]) = 64 KB; epi reuse
  // slot s: K at s*8192, V^T at s*8192+4096 (shorts)

  // 512 threads: each stages one 8-short chunk of K and one of V^T per tile.
  auto STAGE = [&](int slot, int kt) {
    int row = tid >> 3, pseg = tid & 7;
    int gseg = pseg ^ (row & 7);
    gload_lds16(&Kb[((size_t)bh * T_ + kt * 64 + row) * DH + gseg * 8],
                &lds[slot * 8192 + tid * 8]);
    gload_lds16(&Vtb[((size_t)bh * DH + row) * T_ + kt * 64 + gseg * 8],
                &lds[slot * 8192 + 4096 + tid * 8]);
  };

  const int nkt = 4 * qt + 4;
  const int q0 = qt * 256 + w * 32;    // this wave's 32 q-rows
  const int qg = q0 + lq;

  short8 qf[4];
#pragma unroll
  for (int c = 0; c < 4; ++c)
    qf[c] = *(const short8*)&Qb[((size_t)bh * T_ + qg) * DH + c * 16 + hi * 8];
  asm volatile("s_waitcnt vmcnt(0)" ::: "memory");

  float lsum = 0.f;
  f32x16 oacc[2] = {};

  auto CSUB = [&](int kt, const int koff) {
    // ---- S^T = K · Q^T (scores already in exp2 units) ----
    f32x16 a0 = {}, a1 = {};
    __builtin_amdgcn_s_setprio(1);
#pragma unroll
    for (int c = 0; c < 4; ++c) {
      short8 kf0 = *(const short8*)&lds[koff + (lq) * 64 + (((2 * c + hi) ^ (lq & 7)) * 8)];
      short8 kf1 = *(const short8*)&lds[koff + (32 + lq) * 64 + (((2 * c + hi) ^ (lq & 7)) * 8)];
      a0 = __builtin_amdgcn_mfma_f32_32x32x16_bf16(kf0, qf[c], a0, 0, 0, 0);
      a1 = __builtin_amdgcn_mfma_f32_32x32x16_bf16(kf1, qf[c], a1, 0, 0, 0);
    }
    __builtin_amdgcn_s_setprio(0);

    // ---- causal mask (diagonal-crossing tiles only) ----
    if (kt * 64 + 63 > q0) {
#pragma unroll
      for (int r = 0; r < 16; ++r) {
        int kg0 = kt * 64 + (r & 3) + 8 * (r >> 2) + 4 * hi;
        if (kg0 > qg) a0[r] = -1e30f;
        if (kg0 + 32 > qg) a1[r] = -1e30f;
      }
    }

    // ---- p = exp2(s) in place; tree-sum into lsum ----
#pragma unroll
    for (int r = 0; r < 16; ++r) {
      a0[r] = expasm(a0[r]);
      a1[r] = expasm(a1[r]);
    }
    {
      float t[8];
#pragma unroll
      for (int i = 0; i < 8; ++i)
        t[i] = (a0[2 * i] + a0[2 * i + 1]) + (a1[2 * i] + a1[2 * i + 1]);
      float u0 = (t[0] + t[1]) + (t[2] + t[3]);
      float u1 = (t[4] + t[5]) + (t[6] + t[7]);
      lsum += u0 + u1;
    }

    // ---- P -> bf16 B-fragments via cvt_pk + permlane32_swap (T12) ----
    short8 pb[4];
#pragma unroll
    for (int st = 0; st < 2; ++st) {
      const f32x16& P = st ? a1 : a0;
      unsigned x0 = cvtpk(P[0], P[1]);
      unsigned x1 = cvtpk(P[2], P[3]);
      unsigned y0 = cvtpk(P[4], P[5]);
      unsigned y1 = cvtpk(P[6], P[7]);
      uint2v r0 = __builtin_amdgcn_permlane32_swap(x0, y0, false, false);
      uint2v r1 = __builtin_amdgcn_permlane32_swap(x1, y1, false, false);
      unsigned x2 = cvtpk(P[8], P[9]);
      unsigned x3 = cvtpk(P[10], P[11]);
      unsigned y2 = cvtpk(P[12], P[13]);
      unsigned y3 = cvtpk(P[14], P[15]);
      uint2v r2 = __builtin_amdgcn_permlane32_swap(x2, y2, false, false);
      uint2v r3 = __builtin_amdgcn_permlane32_swap(x3, y3, false, false);
      uint4v ta, tb;
      ta[0] = r0[0]; ta[1] = r1[0]; ta[2] = r0[1]; ta[3] = r1[1];
      tb[0] = r2[0]; tb[1] = r3[0]; tb[2] = r2[1]; tb[3] = r3[1];
      pb[st * 2 + 0] = __builtin_bit_cast(short8, ta);
      pb[st * 2 + 1] = __builtin_bit_cast(short8, tb);
    }

    // ---- O^T += V^T · P ----
    __builtin_amdgcn_s_setprio(1);
#pragma unroll
    for (int dt = 0; dt < 2; ++dt) {
#pragma unroll
      for (int c = 0; c < 4; ++c) {
        short8 vf = *(const short8*)&lds[koff + 4096 + (dt * 32 + lq) * 64 +
                                         (((2 * c + hi) ^ (lq & 7)) * 8)];
        oacc[dt] = __builtin_amdgcn_mfma_f32_32x32x16_bf16(vf, pb[c], oacc[dt], 0, 0, 0);
      }
    }
    __builtin_amdgcn_s_setprio(0);
  };

  // ---- pipelined K/V loop: 4-slot ring, stage 2 ahead, ONE barrier/tile ----
  STAGE(0, 0);
  if (nkt > 1) STAGE(1, 1);
#pragma unroll 1
  for (int t = 0; t < nkt; ++t) {
    if (t + 2 < nkt) {
      STAGE((t + 2) & 3, t + 2);
      asm volatile("s_waitcnt vmcnt(4)" ::: "memory");
    } else if (t + 1 < nkt) {
      asm volatile("s_waitcnt vmcnt(2)" ::: "memory");
    } else {
      asm volatile("s_waitcnt vmcnt(0)" ::: "memory");
    }
    __builtin_amdgcn_s_barrier();
    __builtin_amdgcn_sched_barrier(0);
    if (t * 64 <= q0 + 31) CSUB(t, (t & 3) * 8192);
  }

  // ---- epilogue: per-wave-private LDS transpose -> coalesced bf16 stores ----
  lsum += __shfl_xor(lsum, 32);
  __syncthreads();  // all waves done with staging slots
  short* sO = lds + w * 2304;  // [32][72] padded, wave-private (8 x 2304 = 18432)
  float inv = 1.0f / lsum;
#pragma unroll
  for (int dt = 0; dt < 2; ++dt)
#pragma unroll
    for (int r = 0; r < 16; r += 2) {
      int dl = dt * 32 + (r & 3) + 8 * (r >> 2) + 4 * hi;
      *(unsigned*)&sO[lq * 72 + dl] = cvtpk(oacc[dt][r] * inv, oacc[dt][r + 1] * inv);
    }
  asm volatile("s_waitcnt lgkmcnt(0)" ::: "memory");
  __builtin_amdgcn_sched_barrier(0);
  {
    int qr = l >> 1, hf = l & 1;
    const int tg = q0 + qr;
#pragma unroll
    for (int ss = 0; ss < 4; ++ss) {
      short8 v = *(const short8*)&sO[qr * 72 + hf * 32 + ss * 8];
      *(short8*)&Ob[((size_t)(b * T_) + tg) * DM + h * 64 + hf * 32 + ss * 8] = v;
    }
  }
}

extern "C" void kernel_launch(void* const* d_in, const int* in_sizes, int n_in,
                              void* d_out, int out_size, void* d_ws, size_t ws_size,
                              hipStream_t stream) {
  const float* x     = (const float*)d_in[0];   // [4,2048,1024]
  const float* Wqkv  = (const float*)d_in[1];   // [3072,1024]
  const float* Wproj = (const float*)d_in[2];   // [1024,1024]
  float* out = (float*)d_out;

  short* ws = (short*)d_ws;
  short* xbf   = ws;                                  // 8192*1024
  short* wqkvb = xbf + (size_t)M_ * DM;               // 3072*1024
  short* wprjb = wqkvb + (size_t)3 * DM * DM;         // 1024*1024
  short* Qb    = wprjb + (size_t)DM * DM;             // pre-scaled by QSCALE
  short* Kb    = Qb + (size_t)BH * T_ * DH;
  short* Vtb   = Kb + (size_t)BH * T_ * DH;           // transposed [bh][dh][t]
  short* Ob    = Vtb + (size_t)BH * T_ * DH;          // 8192*1024

  const int ncv = (M_ * DM + 3 * DM * DM + DM * DM) / 4;
  k_cvt3<<<(ncv + 255) / 256, 256, 0, stream>>>(
      (const float4*)x, (const float4*)Wqkv, (const float4*)Wproj,
      (ushort4*)xbf, (ushort4*)wqkvb, (ushort4*)wprjb);

  k_gemm_qkv<<<dim3(M_ / 128, 3 * DM / 128), 256, 0, stream>>>(xbf, wqkvb, Qb, Kb, Vtb);
  k_attn12<<<512, 512, 0, stream>>>(Qb, Kb, Vtb, Ob);
  k_gemm_proj<<<dim3(M_ / 128, DM / 128), 256, 0, stream>>>(Ob, wprjb, out);
}